// Round 6
// baseline (313.834 us; speedup 1.0000x reference)
//
#include <hip/hip_runtime.h>
#include <hip/hip_bf16.h>
#include <cstdint>

typedef __attribute__((ext_vector_type(8))) short short8_t;   // 8 x bf16
typedef __attribute__((ext_vector_type(4))) short short4_t;   // 4 x bf16
typedef __attribute__((ext_vector_type(4))) float f32x4_t;    // MFMA acc

#define AS1 __attribute__((address_space(1)))
#define AS3 __attribute__((address_space(3)))

__device__ __forceinline__ void gload_lds16(const void* g, void* l) {
  __builtin_amdgcn_global_load_lds((const AS1 void*)g, (AS3 void*)l, 16, 0, 0);
}

__device__ __forceinline__ short8_t ld8(const __hip_bfloat16* p) {
  return *(const short8_t*)p;
}

// ---------------- fused prep: convert x + transpose all 7 weights ----------------
__global__ __launch_bounds__(256) void k_prep(
    const float* __restrict__ x, __hip_bfloat16* __restrict__ xb,
    const float* __restrict__ wq,  const float* __restrict__ wqp,
    const float* __restrict__ wkp, const float* __restrict__ wdkv,
    const float* __restrict__ wuk, const float* __restrict__ wuv,
    const float* __restrict__ wo,
    __hip_bfloat16* __restrict__ Bt1, __hip_bfloat16* __restrict__ Bt2,
    __hip_bfloat16* __restrict__ woT) {
  __shared__ float t[64][65];
  int bid = blockIdx.x;
  if (bid < 4096) {
    int i = (bid * 256 + threadIdx.x) * 8;
    union { short8_t v; __hip_bfloat16 h[8]; } u;
#pragma unroll
    for (int j = 0; j < 8; ++j) u.h[j] = __float2bfloat16(x[i + j]);
    *(short8_t*)(xb + i) = u.v;
    return;
  }
  bid -= 4096;
  const float* in; __hip_bfloat16* out; int R, C, tile;
  if (bid < 1024)      { in = wq;   out = Bt1;                 R = 2048; C = 2048; tile = bid; }
  else if (bid < 1536) { in = wqp;  out = Bt1 + 2048UL * 2048; R = 2048; C = 1024; tile = bid - 1024; }
  else if (bid < 2048) { in = wkp;  out = Bt1 + 3072UL * 2048; R = 2048; C = 1024; tile = bid - 1536; }
  else if (bid < 2304) { in = wdkv; out = Bt1 + 4096UL * 2048; R = 2048; C = 512;  tile = bid - 2048; }
  else if (bid < 2560) { in = wuk;  out = Bt2;                 R = 512;  C = 2048; tile = bid - 2304; }
  else if (bid < 2816) { in = wuv;  out = Bt2 + 2048UL * 512;  R = 512;  C = 2048; tile = bid - 2560; }
  else                 { in = wo;   out = woT;                 R = 2048; C = 2048; tile = bid - 2816; }
  int nct = C >> 6;
  int ct = tile % nct, rt = tile / nct;
  int r0 = rt << 6, c0 = ct << 6;
#pragma unroll
  for (int i = 0; i < 16; ++i) {
    int idx = i * 256 + threadIdx.x;
    int r = idx >> 6, c = idx & 63;
    t[r][c] = in[(size_t)(r0 + r) * C + c0 + c];
  }
  __syncthreads();
#pragma unroll
  for (int i = 0; i < 16; ++i) {
    int idx = i * 256 + threadIdx.x;
    int c = idx >> 6, r = idx & 63;
    out[(size_t)(c0 + c) * R + r0 + r] = __float2bfloat16(t[r][c]);
  }
}

// ---------------- small ring-3 GEMM (128x128, 4 waves) — used for w_o ----------------
__global__ __launch_bounds__(256) void k_gemm_s(const __hip_bfloat16* __restrict__ A,
                                                const __hip_bfloat16* __restrict__ Bt,
                                                int K, int nbx, float* __restrict__ C,
                                                float alpha) {
  __shared__ __align__(16) __hip_bfloat16 Al[3][128 * 32];
  __shared__ __align__(16) __hip_bfloat16 Bl[3][128 * 32];
  int bx = blockIdx.x % nbx, by = blockIdx.x / nbx;
  int tid = threadIdx.x, lane = tid & 63, w = tid >> 6;
  int L = lane & 15, hi = lane >> 4;
  int wr = (w >> 1) << 6, wc = (w & 1) << 6;
  f32x4_t acc[4][4] = {};
  const __hip_bfloat16* Ag = A + (size_t)(by * 128) * K;
  const __hip_bfloat16* Bg = Bt + (size_t)(bx * 128) * K;
  int rA = w * 16 + (lane >> 2);
  int cA = ((lane & 3) ^ ((lane >> 3) & 3)) * 8;       // inverse-swizzled source chunk
  int NT = K >> 5;

  auto stage = [&](int s) {
    int j = s % 3;
    int k0 = s << 5;
    gload_lds16(Ag + (size_t)rA * K + k0 + cA,        &Al[j][(w * 16) * 32]);
    gload_lds16(Ag + (size_t)(rA + 64) * K + k0 + cA, &Al[j][(64 + w * 16) * 32]);
    gload_lds16(Bg + (size_t)rA * K + k0 + cA,        &Bl[j][(w * 16) * 32]);
    gload_lds16(Bg + (size_t)(rA + 64) * K + k0 + cA, &Bl[j][(64 + w * 16) * 32]);
  };

  stage(0); stage(1);
  asm volatile("s_waitcnt vmcnt(4)\ns_barrier" ::: "memory");

  int hs = hi ^ ((L >> 1) & 3);
  for (int t = 0; t < NT; ++t) {
    int j = t % 3;
    short8_t af[4], bf[4];
#pragma unroll
    for (int m = 0; m < 4; ++m) af[m] = ld8(&Al[j][(wr + 16 * m + L) * 32 + 8 * hs]);
#pragma unroll
    for (int n = 0; n < 4; ++n) bf[n] = ld8(&Bl[j][(wc + 16 * n + L) * 32 + 8 * hs]);
    if (t + 2 < NT) stage(t + 2);
    __builtin_amdgcn_s_setprio(1);
#pragma unroll
    for (int m = 0; m < 4; ++m)
#pragma unroll
      for (int n = 0; n < 4; ++n)
        acc[m][n] = __builtin_amdgcn_mfma_f32_16x16x32_bf16(af[m], bf[n], acc[m][n], 0, 0, 0);
    __builtin_amdgcn_s_setprio(0);
    if (t + 2 < NT)      asm volatile("s_waitcnt vmcnt(4)\ns_barrier" ::: "memory");
    else if (t + 1 < NT) asm volatile("s_waitcnt vmcnt(0)\ns_barrier" ::: "memory");
  }

  int r0 = by * 128 + wr + 4 * hi;
  int c0 = bx * 128 + wc;
  size_t N = (size_t)nbx << 7;
#pragma unroll
  for (int m = 0; m < 4; ++m)
#pragma unroll
    for (int n = 0; n < 4; ++n)
#pragma unroll
      for (int i = 0; i < 4; ++i)
        C[(size_t)(r0 + 16 * m + i) * N + c0 + 16 * n + L] = acc[m][n][i] * alpha;
}

// ---------------- big ring-3 GEMM: 256x128 tile, 8 waves (512 thr), 72 KB LDS ----------
// Same gate arithmetic, 3 loads/thread/stage: prologue vmcnt(3), steady vmcnt(3),
// tail vmcnt(0). Wave grid 4x2 (64x64 each). MODE 2: proj1 epilogue. MODE 3: proj2.
template<int MODE>
__global__ __launch_bounds__(512) void k_gemm_b(const __hip_bfloat16* __restrict__ A,
                                                const __hip_bfloat16* __restrict__ Bt,
                                                int K, int nbx,
                                                void* __restrict__ O0, void* __restrict__ O1,
                                                void* __restrict__ O2, void* __restrict__ O3) {
  __shared__ __align__(16) __hip_bfloat16 Al[3][256 * 32];   // 48 KB
  __shared__ __align__(16) __hip_bfloat16 Bl[3][128 * 32];   // 24 KB
  int bx = blockIdx.x % nbx, by = blockIdx.x / nbx;
  int tid = threadIdx.x, lane = tid & 63, w = tid >> 6;      // w in 0..7
  int L = lane & 15, hi = lane >> 4;
  int wr = (w >> 1) << 6;                                    // 0,64,128,192
  int wc = (w & 1) << 6;                                     // 0,64
  f32x4_t acc[4][4] = {};
  const __hip_bfloat16* Ag = A + (size_t)(by * 256) * K;
  const __hip_bfloat16* Bg = Bt + (size_t)(bx * 128) * K;
  int rA = w * 16 + (lane >> 2);                             // 0..127
  int cA = ((lane & 3) ^ ((lane >> 3) & 3)) * 8;
  int NT = K >> 5;

  auto stage = [&](int s) {
    int j = s % 3;
    int k0 = s << 5;
    gload_lds16(Ag + (size_t)rA * K + k0 + cA,         &Al[j][(w * 16) * 32]);
    gload_lds16(Ag + (size_t)(rA + 128) * K + k0 + cA, &Al[j][(128 + w * 16) * 32]);
    gload_lds16(Bg + (size_t)rA * K + k0 + cA,         &Bl[j][(w * 16) * 32]);
  };

  stage(0); stage(1);
  asm volatile("s_waitcnt vmcnt(3)\ns_barrier" ::: "memory");

  int hs = hi ^ ((L >> 1) & 3);
  for (int t = 0; t < NT; ++t) {
    int j = t % 3;
    short8_t af[4], bf[4];
#pragma unroll
    for (int m = 0; m < 4; ++m) af[m] = ld8(&Al[j][(wr + 16 * m + L) * 32 + 8 * hs]);
#pragma unroll
    for (int n = 0; n < 4; ++n) bf[n] = ld8(&Bl[j][(wc + 16 * n + L) * 32 + 8 * hs]);
    if (t + 2 < NT) stage(t + 2);
    __builtin_amdgcn_s_setprio(1);
#pragma unroll
    for (int m = 0; m < 4; ++m)
#pragma unroll
      for (int n = 0; n < 4; ++n)
        acc[m][n] = __builtin_amdgcn_mfma_f32_16x16x32_bf16(af[m], bf[n], acc[m][n], 0, 0, 0);
    __builtin_amdgcn_s_setprio(0);
    if (t + 2 < NT)      asm volatile("s_waitcnt vmcnt(3)\ns_barrier" ::: "memory");
    else if (t + 1 < NT) asm volatile("s_waitcnt vmcnt(0)\ns_barrier" ::: "memory");
  }

  int r0 = by * 256 + wr + 4 * hi;
  int cb = bx * 128 + wc;

  if (MODE == 2) {
    // proj1: cols 0-2047 q_c*SCALE, 2048-3071 q_r rope, 3072-4095 k_r rope, 4096-4607 ckv
    __hip_bfloat16* qcb = (__hip_bfloat16*)O0;
    __hip_bfloat16* qrb = (__hip_bfloat16*)O1;
    __hip_bfloat16* krb = (__hip_bfloat16*)O2;
    __hip_bfloat16* ckv = (__hip_bfloat16*)O3;
    if (bx < 16) {
      const float SCALE = 0.08838834764831845f;
#pragma unroll
      for (int m = 0; m < 4; ++m)
#pragma unroll
        for (int n = 0; n < 4; ++n)
#pragma unroll
          for (int i = 0; i < 4; ++i)
            qcb[(size_t)(r0 + 16 * m + i) * 2048 + cb + 16 * n + L] =
                __float2bfloat16(acc[m][n][i] * SCALE);
    } else if (bx < 32) {
      bool isq = bx < 24;
      __hip_bfloat16* dst = isq ? qrb : krb;
      float osc = isq ? 0.16832169878499666f : 1.3465735902799727f;  // SCALE_ROPE*YF : YF
      int cbl = cb - (isq ? 2048 : 3072);
      float invf[2];
#pragma unroll
      for (int p = 0; p < 2; ++p) {
        float fi = (float)(16 * p + L);
        float bi = __expf(fi * -0.28782313662425574f);   // 10000^(-i/32)
        float ramp = fminf(fmaxf((fi - 1.0f) * (1.0f / 31.0f), 0.0f), 1.0f);
        invf[p] = bi * (1.0f - ramp * (31.0f / 32.0f));
      }
#pragma unroll
      for (int m = 0; m < 4; ++m)
#pragma unroll
        for (int i = 0; i < 4; ++i) {
          int row = r0 + 16 * m + i;
          float ft = (float)(row & 2047);
#pragma unroll
          for (int p = 0; p < 2; ++p) {
            float sn, cs;
            __sincosf(ft * invf[p], &sn, &cs);
            float x1 = acc[m][p][i], x2 = acc[m][p + 2][i];
            dst[(size_t)row * 1024 + cbl + 16 * p + L] =
                __float2bfloat16((x1 * cs - x2 * sn) * osc);
            dst[(size_t)row * 1024 + cbl + 32 + 16 * p + L] =
                __float2bfloat16((x2 * cs + x1 * sn) * osc);
          }
        }
    } else {
      int cbl = cb - 4096;
#pragma unroll
      for (int m = 0; m < 4; ++m)
#pragma unroll
        for (int n = 0; n < 4; ++n)
#pragma unroll
          for (int i = 0; i < 4; ++i)
            ckv[(size_t)(r0 + 16 * m + i) * 512 + cbl + 16 * n + L] =
                __float2bfloat16(acc[m][n][i]);
    }
  } else if (MODE == 3) {
    // proj2: cols 0-2047 k_c -> kcb; 2048-4095 v_c -> vcb AND vT transposed
    __hip_bfloat16* kcb = (__hip_bfloat16*)O0;
    __hip_bfloat16* vcb = (__hip_bfloat16*)O1;
    __hip_bfloat16* vT  = (__hip_bfloat16*)O2;
    if (bx < 16) {
#pragma unroll
      for (int m = 0; m < 4; ++m)
#pragma unroll
        for (int n = 0; n < 4; ++n)
#pragma unroll
          for (int i = 0; i < 4; ++i)
            kcb[(size_t)(r0 + 16 * m + i) * 2048 + cb + 16 * n + L] =
                __float2bfloat16(acc[m][n][i]);
    } else {
#pragma unroll
      for (int m = 0; m < 4; ++m)
#pragma unroll
        for (int n = 0; n < 4; ++n) {
          int vcol = cb - 2048 + 16 * n + L;      // 0..2047: h*128+dh
          int hh = vcol >> 7, dh = vcol & 127;
          int row0 = r0 + 16 * m;                 // 4 consecutive rows, same b
          int b = row0 >> 11, t0 = row0 & 2047;
          union { short4_t v; __hip_bfloat16 h4[4]; } pk;
#pragma unroll
          for (int i = 0; i < 4; ++i) {
            __hip_bfloat16 bv = __float2bfloat16(acc[m][n][i]);
            vcb[(size_t)(row0 + i) * 2048 + vcol] = bv;
            pk.h4[i] = bv;
          }
          *(short4_t*)(vT + ((size_t)((b * 16 + hh) * 128 + dh) * 2048 + t0)) = pk.v;
        }
    }
  }
}

// ---------------- flash-style SPARSE attention with T14 async-stage split ----------
// Explicit step list; tile i+1's K/V prefetched into registers during tile i's
// compute; regs -> LDS at next iteration top (auto vmcnt wait).
__global__ __launch_bounds__(256) void k_attn(const __hip_bfloat16* __restrict__ qc,
                                              const __hip_bfloat16* __restrict__ kc,
                                              const __hip_bfloat16* __restrict__ vcb,
                                              const __hip_bfloat16* __restrict__ qr,
                                              const __hip_bfloat16* __restrict__ kr,
                                              const __hip_bfloat16* __restrict__ vT,
                                              __hip_bfloat16* __restrict__ ao) {
  const int T = 2048;
  int bid = blockIdx.x;
  int xcd = bid & 7, rr0 = bid >> 3;
  int jj0 = rr0 >> 5, qt = rr0 & 31;
  int bh = xcd + 8 * jj0;
  int b = bh >> 4, h = bh & 15;
  int tid = threadIdx.x, lane = tid & 63, w = tid >> 6;
  int L = lane & 15, hi = lane >> 4;
  int q0 = qt * 64;

  __shared__ __align__(16) __hip_bfloat16 Kl[64 * 200];
  __shared__ __align__(16) __hip_bfloat16 Vt[128 * 64];
  __shared__ __align__(16) __hip_bfloat16 Pl[4][16 * 72];

  char* Vtb = (char*)Vt;
  const __hip_bfloat16* vTb = vT + (size_t)(b * 16 + h) * 128 * 2048;

  int qrow = q0 + w * 16 + L;
  size_t qb = (size_t)b * T + qrow;
  short8_t qf[6];
#pragma unroll
  for (int c = 0; c < 4; ++c)
    qf[c] = ld8(qc + qb * 2048 + h * 128 + 32 * c + 8 * hi);
#pragma unroll
  for (int c = 0; c < 2; ++c)
    qf[4 + c] = ld8(qr + qb * 1024 + h * 64 + 32 * c + 8 * hi);

  f32x4_t oacc[8] = {};
  float mrow[4], lrow[4];
#pragma unroll
  for (int i = 0; i < 4; ++i) { mrow[i] = -1e30f; lrow[i] = 0.0f; }

  int nd = qt - 6;

  // step list: full tiles {0,1} U {qt-4..qt}, then compact (marker -1)
  int k0s[9]; int ns = 0;
  if (qt <= 6) {
    for (int s = 0; s <= qt; ++s) k0s[ns++] = s * 64;
  } else {
    k0s[ns++] = 0; k0s[ns++] = 64;
    for (int s = qt - 4; s <= qt; ++s) k0s[ns++] = s * 64;
    if (nd > 0) k0s[ns++] = -1;
  }

  short8_t kpre[6], vpre[4];

  auto loadKV = [&](int idx) {
    bool cp = (k0s[idx] < 0);
    int k0 = cp ? 0 : k0s[idx];
#pragma unroll
    for (int i = 0; i < 6; ++i) {
      int ch = i * 256 + tid;
      int r = ch / 24, d = (ch % 24) * 8;
      int srcr = cp ? ((r < nd) ? 64 * (2 + r) : 0) : (k0 + r);
      size_t krow = (size_t)b * T + srcr;
      kpre[i] = (d < 128) ? ld8(kc + krow * 2048 + h * 128 + d)
                          : ld8(kr + krow * 1024 + h * 64 + (d - 128));
    }
    if (!cp) {
#pragma unroll
      for (int i = 0; i < 4; ++i) {
        int ch = i * 256 + tid;
        int row = ch >> 3, c = ch & 7;
        vpre[i] = ld8(vTb + (size_t)row * 2048 + k0 + c * 8);
      }
    } else {
#pragma unroll
      for (int i = 0; i < 2; ++i) {
        int ch = i * 256 + tid;
        int jj = ch >> 4, d0 = (ch & 15) * 8;
        int jje = (jj < nd) ? jj : 0;
        vpre[i] = ld8(vcb + (size_t)(b * 2048 + 64 * (2 + jje)) * 2048 + h * 128 + d0);
      }
    }
  };

  auto writeKV = [&](int idx) {
    bool cp = (k0s[idx] < 0);
#pragma unroll
    for (int i = 0; i < 6; ++i) {
      int ch = i * 256 + tid;
      int r = ch / 24, d = (ch % 24) * 8;
      *(short8_t*)(Kl + r * 200 + d) = kpre[i];
    }
    if (!cp) {
#pragma unroll
      for (int i = 0; i < 4; ++i) {
        int ch = i * 256 + tid;
        int row = ch >> 3, c = ch & 7;
        int swc = c ^ (row & 7);
        *(short8_t*)(Vtb + row * 128 + 16 * swc) = vpre[i];
      }
    } else {
#pragma unroll
      for (int i = 0; i < 2; ++i) {
        int ch = i * 256 + tid;
        int jj = ch >> 4, d0 = (ch & 15) * 8;
        if (jj < nd) {
          union { short8_t v; __hip_bfloat16 hh[8]; } u;
          u.v = vpre[i];
#pragma unroll
          for (int qq = 0; qq < 8; ++qq) {
            int dh = d0 + qq;
            int swc = (jj >> 3) ^ (dh & 7);
            *(__hip_bfloat16*)(Vtb + dh * 128 + 16 * swc + 2 * (jj & 7)) = u.hh[qq];
          }
        }
      }
    }
  };

  loadKV(0);

  for (int it = 0; it < ns; ++it) {
    bool compact = (k0s[it] < 0);
    int k0 = compact ? 0 : k0s[it];

    writeKV(it);               // auto s_waitcnt on kpre/vpre
    __syncthreads();
    if (it + 1 < ns) loadKV(it + 1);   // issue next tile's loads early (T14)

    // ---- S = Q_cat @ K_cat^T ----
    f32x4_t sacc[4] = {};
    __builtin_amdgcn_s_setprio(1);
#pragma unroll
    for (int n = 0; n < 4; ++n)
#pragma unroll
      for (int c = 0; c < 6; ++c) {
        short8_t bfr = ld8(Kl + (16 * n + L) * 200 + 32 * c + 8 * hi);
        sacc[n] = __builtin_amdgcn_mfma_f32_16x16x32_bf16(qf[c], bfr, sacc[n], 0, 0, 0);
      }
    __builtin_amdgcn_s_setprio(0);

    // ---- mask + online softmax ----
    int rbase = q0 + w * 16 + 4 * hi;
    float p[4][4];
    float mt[4];
#pragma unroll
    for (int i = 0; i < 4; ++i) mt[i] = -1e30f;
#pragma unroll
    for (int n = 0; n < 4; ++n) {
      int col = L + 16 * n;
      int k = k0 + col;
#pragma unroll
      for (int i = 0; i < 4; ++i) {
        int rq = rbase + i;
        bool ok = compact ? (col < nd)
                          : ((k <= rq) && ((rq - k <= 256) || ((k & 63) == 0) || (k < 128)));
        float s = ok ? sacc[n][i] : -1e30f;
        p[n][i] = s;
        mt[i] = fmaxf(mt[i], s);
      }
    }
    for (int d = 1; d < 16; d <<= 1)
#pragma unroll
      for (int i = 0; i < 4; ++i) mt[i] = fmaxf(mt[i], __shfl_xor(mt[i], d, 64));
    float al[4], rs[4];
#pragma unroll
    for (int i = 0; i < 4; ++i) {
      float mnew = fmaxf(mrow[i], mt[i]);
      al[i] = __expf(mrow[i] - mnew);
      mrow[i] = mnew;
      rs[i] = 0.0f;
    }
#pragma unroll
    for (int n = 0; n < 4; ++n)
#pragma unroll
      for (int i = 0; i < 4; ++i) {
        float e = __expf(p[n][i] - mrow[i]);
        p[n][i] = e;
        rs[i] += e;
      }
    for (int d = 1; d < 16; d <<= 1)
#pragma unroll
      for (int i = 0; i < 4; ++i) rs[i] += __shfl_xor(rs[i], d, 64);
#pragma unroll
    for (int i = 0; i < 4; ++i) lrow[i] = lrow[i] * al[i] + rs[i];
#pragma unroll
    for (int n = 0; n < 8; ++n)
#pragma unroll
      for (int i = 0; i < 4; ++i) oacc[n][i] *= al[i];

    // ---- P -> LDS (per-wave buffer; same-wave read, no barrier needed) ----
#pragma unroll
    for (int n = 0; n < 4; ++n)
#pragma unroll
      for (int i = 0; i < 4; ++i)
        Pl[w][(4 * hi + i) * 72 + 16 * n + L] = __float2bfloat16(p[n][i]);

    // ---- O += P @ V ----
    __builtin_amdgcn_s_setprio(1);
#pragma unroll
    for (int ks = 0; ks < 2; ++ks) {
      short8_t pa = ld8(Pl[w] + L * 72 + 32 * ks + 8 * hi);
#pragma unroll
      for (int n = 0; n < 8; ++n) {
        int vrow = 16 * n + L;
        int chunk = (4 * ks + hi) ^ (vrow & 7);
        short8_t bv = *(const short8_t*)(Vtb + vrow * 128 + 16 * chunk);
        oacc[n] = __builtin_amdgcn_mfma_f32_16x16x32_bf16(pa, bv, oacc[n], 0, 0, 0);
      }
    }
    __builtin_amdgcn_s_setprio(0);
    __syncthreads();
  }

  // ---- epilogue ----
#pragma unroll
  for (int n = 0; n < 8; ++n)
#pragma unroll
    for (int i = 0; i < 4; ++i) {
      int rq = q0 + w * 16 + 4 * hi + i;
      int cdh = 16 * n + L;
      float v = oacc[n][i] / lrow[i];
      ao[((size_t)b * T + rq) * 2048 + h * 128 + cdh] = __float2bfloat16(v);
    }
}

// ---------------- host ----------------
extern "C" void kernel_launch(void* const* d_in, const int* in_sizes, int n_in,
                              void* d_out, int out_size, void* d_ws, size_t ws_size,
                              hipStream_t stream) {
  const float* x     = (const float*)d_in[0];
  const float* w_q   = (const float*)d_in[1];
  const float* w_dkv = (const float*)d_in[2];
  const float* w_uk  = (const float*)d_in[3];
  const float* w_uv  = (const float*)d_in[4];
  const float* w_qp  = (const float*)d_in[5];
  const float* w_kp  = (const float*)d_in[6];
  const float* w_o   = (const float*)d_in[7];
  float* out = (float*)d_out;

  char* ws = (char*)d_ws;
  size_t off = 0;
  auto alloc = [&](size_t elems) {
    __hip_bfloat16* p = (__hip_bfloat16*)(ws + off);
    off += ((elems * 2 + 255) & ~(size_t)255);
    return p;
  };
  __hip_bfloat16* xb  = alloc(8388608);            // x bf16 [4096][2048]
  __hip_bfloat16* Bt1 = alloc(4608UL * 2048);      // [wq^T; wqp^T; wkp^T; wdkv^T]
  __hip_bfloat16* Bt2 = alloc(4096UL * 512);       // [wuk^T; wuv^T]
  __hip_bfloat16* woT = alloc(4194304);
  __hip_bfloat16* qcb = alloc(8388608);
  __hip_bfloat16* ckv = alloc(2097152);
  __hip_bfloat16* kcb = alloc(8388608);
  __hip_bfloat16* vcb = alloc(8388608);
  __hip_bfloat16* qrb = alloc(4194304);
  __hip_bfloat16* krb = alloc(4194304);
  __hip_bfloat16* aob = alloc(8388608);
  __hip_bfloat16* vT  = alloc(8388608);            // [32][128][2048]

  k_prep<<<7936, 256, 0, stream>>>(x, xb, w_q, w_qp, w_kp, w_dkv, w_uk, w_uv, w_o,
                                   Bt1, Bt2, woT);

  k_gemm_b<2><<<36 * 16, 512, 0, stream>>>(xb, Bt1, 2048, 36, qcb, qrb, krb, ckv);
  k_gemm_b<3><<<32 * 16, 512, 0, stream>>>(ckv, Bt2, 512, 32, kcb, vcb, vT, nullptr);

  k_attn<<<1024, 256, 0, stream>>>(qcb, kcb, vcb, qrb, krb, vT, aob);

  k_gemm_s<<<16 * 32, 256, 0, stream>>>(aob, woT, 2048, 16, out, 1.0f);
}

// Round 7
// 273.223 us; speedup vs baseline: 1.1486x; 1.1486x over previous
//
#include <hip/hip_runtime.h>
#include <hip/hip_bf16.h>
#include <cstdint>

typedef __attribute__((ext_vector_type(8))) short short8_t;   // 8 x bf16
typedef __attribute__((ext_vector_type(4))) short short4_t;   // 4 x bf16
typedef __attribute__((ext_vector_type(4))) float f32x4_t;    // MFMA acc

#define AS1 __attribute__((address_space(1)))
#define AS3 __attribute__((address_space(3)))

__device__ __forceinline__ void gload_lds16(const void* g, void* l) {
  __builtin_amdgcn_global_load_lds((const AS1 void*)g, (AS3 void*)l, 16, 0, 0);
}

__device__ __forceinline__ short8_t ld8(const __hip_bfloat16* p) {
  return *(const short8_t*)p;
}

// ---------------- fused prep: convert x + transpose all 7 weights ----------------
__global__ __launch_bounds__(256) void k_prep(
    const float* __restrict__ x, __hip_bfloat16* __restrict__ xb,
    const float* __restrict__ wq,  const float* __restrict__ wqp,
    const float* __restrict__ wkp, const float* __restrict__ wdkv,
    const float* __restrict__ wuk, const float* __restrict__ wuv,
    const float* __restrict__ wo,
    __hip_bfloat16* __restrict__ Bt1, __hip_bfloat16* __restrict__ Bt2,
    __hip_bfloat16* __restrict__ woT) {
  __shared__ float t[64][65];
  int bid = blockIdx.x;
  if (bid < 4096) {
    int i = (bid * 256 + threadIdx.x) * 8;
    union { short8_t v; __hip_bfloat16 h[8]; } u;
#pragma unroll
    for (int j = 0; j < 8; ++j) u.h[j] = __float2bfloat16(x[i + j]);
    *(short8_t*)(xb + i) = u.v;
    return;
  }
  bid -= 4096;
  const float* in; __hip_bfloat16* out; int R, C, tile;
  if (bid < 1024)      { in = wq;   out = Bt1;                 R = 2048; C = 2048; tile = bid; }
  else if (bid < 1536) { in = wqp;  out = Bt1 + 2048UL * 2048; R = 2048; C = 1024; tile = bid - 1024; }
  else if (bid < 2048) { in = wkp;  out = Bt1 + 3072UL * 2048; R = 2048; C = 1024; tile = bid - 1536; }
  else if (bid < 2304) { in = wdkv; out = Bt1 + 4096UL * 2048; R = 2048; C = 512;  tile = bid - 2048; }
  else if (bid < 2560) { in = wuk;  out = Bt2;                 R = 512;  C = 2048; tile = bid - 2304; }
  else if (bid < 2816) { in = wuv;  out = Bt2 + 2048UL * 512;  R = 512;  C = 2048; tile = bid - 2560; }
  else                 { in = wo;   out = woT;                 R = 2048; C = 2048; tile = bid - 2816; }
  int nct = C >> 6;
  int ct = tile % nct, rt = tile / nct;
  int r0 = rt << 6, c0 = ct << 6;
#pragma unroll
  for (int i = 0; i < 16; ++i) {
    int idx = i * 256 + threadIdx.x;
    int r = idx >> 6, c = idx & 63;
    t[r][c] = in[(size_t)(r0 + r) * C + c0 + c];
  }
  __syncthreads();
#pragma unroll
  for (int i = 0; i < 16; ++i) {
    int idx = i * 256 + threadIdx.x;
    int c = idx >> 6, r = idx & 63;
    out[(size_t)(c0 + c) * R + r0 + r] = __float2bfloat16(t[r][c]);
  }
}

// ---------------- ring-3 pipelined GEMM (R5-proven): 128x128, 4 waves, 48 KB LDS ----
template<int MODE>
__global__ __launch_bounds__(256) void k_gemm2(const __hip_bfloat16* __restrict__ A,
                                               const __hip_bfloat16* __restrict__ Bt,
                                               int K, int nbx,
                                               void* __restrict__ O0, void* __restrict__ O1,
                                               void* __restrict__ O2, void* __restrict__ O3,
                                               float alpha) {
  __shared__ __align__(16) __hip_bfloat16 Al[3][128 * 32];
  __shared__ __align__(16) __hip_bfloat16 Bl[3][128 * 32];
  int bx = blockIdx.x % nbx, by = blockIdx.x / nbx;
  int tid = threadIdx.x, lane = tid & 63, w = tid >> 6;
  int L = lane & 15, hi = lane >> 4;
  int wr = (w >> 1) << 6, wc = (w & 1) << 6;
  f32x4_t acc[4][4] = {};
  const __hip_bfloat16* Ag = A + (size_t)(by * 128) * K;
  const __hip_bfloat16* Bg = Bt + (size_t)(bx * 128) * K;
  int rA = w * 16 + (lane >> 2);
  int cA = ((lane & 3) ^ ((lane >> 3) & 3)) * 8;       // inverse-swizzled source chunk
  int NT = K >> 5;

  auto stage = [&](int s) {
    int j = s % 3;
    int k0 = s << 5;
    gload_lds16(Ag + (size_t)rA * K + k0 + cA,        &Al[j][(w * 16) * 32]);
    gload_lds16(Ag + (size_t)(rA + 64) * K + k0 + cA, &Al[j][(64 + w * 16) * 32]);
    gload_lds16(Bg + (size_t)rA * K + k0 + cA,        &Bl[j][(w * 16) * 32]);
    gload_lds16(Bg + (size_t)(rA + 64) * K + k0 + cA, &Bl[j][(64 + w * 16) * 32]);
  };

  stage(0); stage(1);
  asm volatile("s_waitcnt vmcnt(4)\ns_barrier" ::: "memory");

  int hs = hi ^ ((L >> 1) & 3);
  for (int t = 0; t < NT; ++t) {
    int j = t % 3;
    short8_t af[4], bf[4];
#pragma unroll
    for (int m = 0; m < 4; ++m) af[m] = ld8(&Al[j][(wr + 16 * m + L) * 32 + 8 * hs]);
#pragma unroll
    for (int n = 0; n < 4; ++n) bf[n] = ld8(&Bl[j][(wc + 16 * n + L) * 32 + 8 * hs]);
    if (t + 2 < NT) stage(t + 2);
    __builtin_amdgcn_s_setprio(1);
#pragma unroll
    for (int m = 0; m < 4; ++m)
#pragma unroll
      for (int n = 0; n < 4; ++n)
        acc[m][n] = __builtin_amdgcn_mfma_f32_16x16x32_bf16(af[m], bf[n], acc[m][n], 0, 0, 0);
    __builtin_amdgcn_s_setprio(0);
    if (t + 2 < NT)      asm volatile("s_waitcnt vmcnt(4)\ns_barrier" ::: "memory");
    else if (t + 1 < NT) asm volatile("s_waitcnt vmcnt(0)\ns_barrier" ::: "memory");
  }

  int r0 = by * 128 + wr + 4 * hi;
  int cb = bx * 128 + wc;

  if (MODE == 1) {
    float* C = (float*)O0;
    size_t N = (size_t)nbx << 7;
#pragma unroll
    for (int m = 0; m < 4; ++m)
#pragma unroll
      for (int n = 0; n < 4; ++n)
#pragma unroll
        for (int i = 0; i < 4; ++i)
          C[(size_t)(r0 + 16 * m + i) * N + cb + 16 * n + L] = acc[m][n][i] * alpha;
  } else if (MODE == 2) {
    __hip_bfloat16* qcb = (__hip_bfloat16*)O0;
    __hip_bfloat16* qrb = (__hip_bfloat16*)O1;
    __hip_bfloat16* krb = (__hip_bfloat16*)O2;
    __hip_bfloat16* ckv = (__hip_bfloat16*)O3;
    if (bx < 16) {
      const float SCALE = 0.08838834764831845f;
#pragma unroll
      for (int m = 0; m < 4; ++m)
#pragma unroll
        for (int n = 0; n < 4; ++n)
#pragma unroll
          for (int i = 0; i < 4; ++i)
            qcb[(size_t)(r0 + 16 * m + i) * 2048 + cb + 16 * n + L] =
                __float2bfloat16(acc[m][n][i] * SCALE);
    } else if (bx < 32) {
      bool isq = bx < 24;
      __hip_bfloat16* dst = isq ? qrb : krb;
      float osc = isq ? 0.16832169878499666f : 1.3465735902799727f;  // SCALE_ROPE*YF : YF
      int cbl = cb - (isq ? 2048 : 3072);
      float invf[2];
#pragma unroll
      for (int p = 0; p < 2; ++p) {
        float fi = (float)(16 * p + L);
        float bi = __expf(fi * -0.28782313662425574f);   // 10000^(-i/32)
        float ramp = fminf(fmaxf((fi - 1.0f) * (1.0f / 31.0f), 0.0f), 1.0f);
        invf[p] = bi * (1.0f - ramp * (31.0f / 32.0f));
      }
#pragma unroll
      for (int m = 0; m < 4; ++m)
#pragma unroll
        for (int i = 0; i < 4; ++i) {
          int row = r0 + 16 * m + i;
          float ft = (float)(row & 2047);
#pragma unroll
          for (int p = 0; p < 2; ++p) {
            float sn, cs;
            __sincosf(ft * invf[p], &sn, &cs);
            float x1 = acc[m][p][i], x2 = acc[m][p + 2][i];
            dst[(size_t)row * 1024 + cbl + 16 * p + L] =
                __float2bfloat16((x1 * cs - x2 * sn) * osc);
            dst[(size_t)row * 1024 + cbl + 32 + 16 * p + L] =
                __float2bfloat16((x2 * cs + x1 * sn) * osc);
          }
        }
    } else {
      int cbl = cb - 4096;
#pragma unroll
      for (int m = 0; m < 4; ++m)
#pragma unroll
        for (int n = 0; n < 4; ++n)
#pragma unroll
          for (int i = 0; i < 4; ++i)
            ckv[(size_t)(r0 + 16 * m + i) * 512 + cbl + 16 * n + L] =
                __float2bfloat16(acc[m][n][i]);
    }
  } else if (MODE == 3) {
    __hip_bfloat16* kcb = (__hip_bfloat16*)O0;
    __hip_bfloat16* vcb = (__hip_bfloat16*)O1;
    __hip_bfloat16* vT  = (__hip_bfloat16*)O2;
    if (bx < 16) {
#pragma unroll
      for (int m = 0; m < 4; ++m)
#pragma unroll
        for (int n = 0; n < 4; ++n)
#pragma unroll
          for (int i = 0; i < 4; ++i)
            kcb[(size_t)(r0 + 16 * m + i) * 2048 + cb + 16 * n + L] =
                __float2bfloat16(acc[m][n][i]);
    } else {
#pragma unroll
      for (int m = 0; m < 4; ++m)
#pragma unroll
        for (int n = 0; n < 4; ++n) {
          int vcol = cb - 2048 + 16 * n + L;      // 0..2047: h*128+dh
          int hh = vcol >> 7, dh = vcol & 127;
          int row0 = r0 + 16 * m;                 // 4 consecutive rows, same b
          int b = row0 >> 11, t0 = row0 & 2047;
          union { short4_t v; __hip_bfloat16 h4[4]; } pk;
#pragma unroll
          for (int i = 0; i < 4; ++i) {
            __hip_bfloat16 bv = __float2bfloat16(acc[m][n][i]);
            vcb[(size_t)(row0 + i) * 2048 + vcol] = bv;
            pk.h4[i] = bv;
          }
          *(short4_t*)(vT + ((size_t)((b * 16 + hh) * 128 + dh) * 2048 + t0)) = pk.v;
        }
    }
  }
}

// ---------------- flash-style SPARSE attention, SPLIT-K (flash-decoding) ----------
// 2048 blocks: (b,h,qt,half). Each half processes a contiguous slice of the tile
// list and stores UNNORMALIZED partials: po = sum(e^{s-m} v), ml = (m, l).
// Inner tile body is the R5-proven structure, unchanged.
__global__ __launch_bounds__(256) void k_attn_part(const __hip_bfloat16* __restrict__ qc,
                                                   const __hip_bfloat16* __restrict__ kc,
                                                   const __hip_bfloat16* __restrict__ vcb,
                                                   const __hip_bfloat16* __restrict__ qr,
                                                   const __hip_bfloat16* __restrict__ kr,
                                                   const __hip_bfloat16* __restrict__ vT,
                                                   __hip_bfloat16* __restrict__ po,
                                                   float* __restrict__ ml) {
  const int T = 2048;
  int bid = blockIdx.x;
  int xcd = bid & 7, r = bid >> 3;           // r: 0..255
  int qt = r & 31;
  int half = (r >> 5) & 1;
  int jg = r >> 6;                           // 0..3
  int bh = xcd + 8 * jg;
  int b = bh >> 4, h = bh & 15;
  int tid = threadIdx.x, lane = tid & 63, w = tid >> 6;
  int L = lane & 15, hi = lane >> 4;
  int q0 = qt * 64;

  __shared__ __align__(16) __hip_bfloat16 Kl[64 * 200];
  __shared__ __align__(16) __hip_bfloat16 Vt[128 * 64];
  __shared__ __align__(16) __hip_bfloat16 Pl[4][16 * 72];

  char* Vtb = (char*)Vt;
  const __hip_bfloat16* vTb = vT + (size_t)(b * 16 + h) * 128 * 2048;

  int qrow = q0 + w * 16 + L;
  size_t qb = (size_t)b * T + qrow;
  short8_t qf[6];
#pragma unroll
  for (int c = 0; c < 4; ++c)
    qf[c] = ld8(qc + qb * 2048 + h * 128 + 32 * c + 8 * hi);
#pragma unroll
  for (int c = 0; c < 2; ++c)
    qf[4 + c] = ld8(qr + qb * 1024 + h * 64 + 32 * c + 8 * hi);

  f32x4_t oacc[8] = {};
  float mrow[4], lrow[4];
#pragma unroll
  for (int i = 0; i < 4; ++i) { mrow[i] = -1e30f; lrow[i] = 0.0f; }

  int nd = qt - 6;

  // tile list: {0,1} U {qt-4..qt} U {compact}, split contiguously between halves
  int k0s[9]; int ns = 0;
  if (qt <= 6) {
    for (int s = 0; s <= qt; ++s) k0s[ns++] = s * 64;
  } else {
    k0s[ns++] = 0; k0s[ns++] = 64;
    for (int s = qt - 4; s <= qt; ++s) k0s[ns++] = s * 64;
    if (nd > 0) k0s[ns++] = -1;
  }
  int h0 = (ns + 1) >> 1;
  int ibeg = half ? h0 : 0;
  int iend = half ? ns : h0;

  for (int it = ibeg; it < iend; ++it) {
    bool compact = (k0s[it] < 0);
    int k0 = compact ? 0 : k0s[it];

    if (!compact) {
#pragma unroll
      for (int i = 0; i < 6; ++i) {
        int ch = i * 256 + tid;
        int rr = ch / 24;
        int d = (ch % 24) * 8;
        size_t krow = (size_t)b * T + k0 + rr;
        const __hip_bfloat16* src = (d < 128)
            ? kc + krow * 2048 + h * 128 + d
            : kr + krow * 1024 + h * 64 + (d - 128);
        *(short8_t*)(Kl + rr * 200 + d) = ld8(src);
      }
#pragma unroll
      for (int i = 0; i < 4; ++i) {
        int ch = i * 256 + tid;
        int row = ch >> 3, c = ch & 7;
        int swc = c ^ (row & 7);
        *(short8_t*)(Vtb + row * 128 + 16 * swc) = ld8(vTb + (size_t)row * 2048 + k0 + c * 8);
      }
    } else {
#pragma unroll
      for (int i = 0; i < 6; ++i) {
        int ch = i * 256 + tid;
        int rr = ch / 24;
        int d = (ch % 24) * 8;
        int srcr = (rr < nd) ? 64 * (2 + rr) : 0;
        size_t krow = (size_t)b * T + srcr;
        const __hip_bfloat16* src = (d < 128)
            ? kc + krow * 2048 + h * 128 + d
            : kr + krow * 1024 + h * 64 + (d - 128);
        *(short8_t*)(Kl + rr * 200 + d) = ld8(src);
      }
#pragma unroll
      for (int i = 0; i < 2; ++i) {
        int ch = i * 256 + tid;
        int jj = ch >> 4, d0 = (ch & 15) * 8;
        if (jj < nd) {
          union { short8_t v; __hip_bfloat16 hh[8]; } u;
          u.v = ld8(vcb + (size_t)(b * 2048 + 64 * (2 + jj)) * 2048 + h * 128 + d0);
#pragma unroll
          for (int qq = 0; qq < 8; ++qq) {
            int dh = d0 + qq;
            int swc = (jj >> 3) ^ (dh & 7);
            *(__hip_bfloat16*)(Vtb + dh * 128 + 16 * swc + 2 * (jj & 7)) = u.hh[qq];
          }
        }
      }
    }
    __syncthreads();

    f32x4_t sacc[4] = {};
    __builtin_amdgcn_s_setprio(1);
#pragma unroll
    for (int n = 0; n < 4; ++n)
#pragma unroll
      for (int c = 0; c < 6; ++c) {
        short8_t bfr = ld8(Kl + (16 * n + L) * 200 + 32 * c + 8 * hi);
        sacc[n] = __builtin_amdgcn_mfma_f32_16x16x32_bf16(qf[c], bfr, sacc[n], 0, 0, 0);
      }
    __builtin_amdgcn_s_setprio(0);

    int rbase = q0 + w * 16 + 4 * hi;
    float p[4][4];
    float mt[4];
#pragma unroll
    for (int i = 0; i < 4; ++i) mt[i] = -1e30f;
#pragma unroll
    for (int n = 0; n < 4; ++n) {
      int col = L + 16 * n;
      int k = k0 + col;
#pragma unroll
      for (int i = 0; i < 4; ++i) {
        int rq = rbase + i;
        bool ok = compact ? (col < nd)
                          : ((k <= rq) && ((rq - k <= 256) || ((k & 63) == 0) || (k < 128)));
        float s = ok ? sacc[n][i] : -1e30f;
        p[n][i] = s;
        mt[i] = fmaxf(mt[i], s);
      }
    }
    for (int d = 1; d < 16; d <<= 1)
#pragma unroll
      for (int i = 0; i < 4; ++i) mt[i] = fmaxf(mt[i], __shfl_xor(mt[i], d, 64));
    float al[4], rs[4];
#pragma unroll
    for (int i = 0; i < 4; ++i) {
      float mnew = fmaxf(mrow[i], mt[i]);
      al[i] = __expf(mrow[i] - mnew);
      mrow[i] = mnew;
      rs[i] = 0.0f;
    }
#pragma unroll
    for (int n = 0; n < 4; ++n)
#pragma unroll
      for (int i = 0; i < 4; ++i) {
        float e = __expf(p[n][i] - mrow[i]);
        p[n][i] = e;
        rs[i] += e;
      }
    for (int d = 1; d < 16; d <<= 1)
#pragma unroll
      for (int i = 0; i < 4; ++i) rs[i] += __shfl_xor(rs[i], d, 64);
#pragma unroll
    for (int i = 0; i < 4; ++i) lrow[i] = lrow[i] * al[i] + rs[i];
#pragma unroll
    for (int n = 0; n < 8; ++n)
#pragma unroll
      for (int i = 0; i < 4; ++i) oacc[n][i] *= al[i];

#pragma unroll
    for (int n = 0; n < 4; ++n)
#pragma unroll
      for (int i = 0; i < 4; ++i)
        Pl[w][(4 * hi + i) * 72 + 16 * n + L] = __float2bfloat16(p[n][i]);
    __syncthreads();

    __builtin_amdgcn_s_setprio(1);
#pragma unroll
    for (int ks = 0; ks < 2; ++ks) {
      short8_t pa = ld8(Pl[w] + L * 72 + 32 * ks + 8 * hi);
#pragma unroll
      for (int n = 0; n < 8; ++n) {
        int vrow = 16 * n + L;
        int chunk = (4 * ks + hi) ^ (vrow & 7);
        short8_t bv = *(const short8_t*)(Vtb + vrow * 128 + 16 * chunk);
        oacc[n] = __builtin_amdgcn_mfma_f32_16x16x32_bf16(pa, bv, oacc[n], 0, 0, 0);
      }
    }
    __builtin_amdgcn_s_setprio(0);
    __syncthreads();
  }

  // ---- partial epilogue: store raw O, m, l ----
  __hip_bfloat16* pod = po + (size_t)half * 8388608;
#pragma unroll
  for (int n = 0; n < 8; ++n)
#pragma unroll
    for (int i = 0; i < 4; ++i) {
      int rq = q0 + w * 16 + 4 * hi + i;
      int cdh = 16 * n + L;
      pod[((size_t)b * T + rq) * 2048 + h * 128 + cdh] = __float2bfloat16(oacc[n][i]);
    }
  if (L == 0) {
#pragma unroll
    for (int i = 0; i < 4; ++i) {
      int rq = q0 + w * 16 + 4 * hi + i;
      size_t o = (((size_t)half * 4096 + b * 2048 + rq) * 16 + h) * 2;
      ml[o] = mrow[i];
      ml[o + 1] = lrow[i];
    }
  }
}

// ---------------- combine: merge two halves (flash-decoding rescale) ----------------
__global__ __launch_bounds__(256) void k_combine(const __hip_bfloat16* __restrict__ po,
                                                 const float* __restrict__ ml,
                                                 __hip_bfloat16* __restrict__ ao) {
  int idx = blockIdx.x * 256 + threadIdx.x;     // 1,048,576 threads
  int row = idx >> 8;                            // 0..4095 (b*2048+t)
  int col = (idx & 255) * 8;
  int h = col >> 7;
  size_t mo = ((size_t)row * 16 + h) * 2;
  float m1 = ml[mo],                    l1 = ml[mo + 1];
  float m2 = ml[mo + 4096 * 16 * 2],    l2 = ml[mo + 4096 * 16 * 2 + 1];
  float m = fmaxf(m1, m2);
  float w1 = __expf(m1 - m), w2 = __expf(m2 - m);
  float inv = 1.0f / (w1 * l1 + w2 * l2);
  size_t o = (size_t)row * 2048 + col;
  union { short8_t v; __hip_bfloat16 h8[8]; } a, bb, c;
  a.v = *(const short8_t*)(po + o);
  bb.v = *(const short8_t*)(po + 8388608 + o);
#pragma unroll
  for (int j = 0; j < 8; ++j)
    c.h8[j] = __float2bfloat16(
        (w1 * __bfloat162float(a.h8[j]) + w2 * __bfloat162float(bb.h8[j])) * inv);
  *(short8_t*)(ao + o) = c.v;
}

// ---------------- host ----------------
extern "C" void kernel_launch(void* const* d_in, const int* in_sizes, int n_in,
                              void* d_out, int out_size, void* d_ws, size_t ws_size,
                              hipStream_t stream) {
  const float* x     = (const float*)d_in[0];
  const float* w_q   = (const float*)d_in[1];
  const float* w_dkv = (const float*)d_in[2];
  const float* w_uk  = (const float*)d_in[3];
  const float* w_uv  = (const float*)d_in[4];
  const float* w_qp  = (const float*)d_in[5];
  const float* w_kp  = (const float*)d_in[6];
  const float* w_o   = (const float*)d_in[7];
  float* out = (float*)d_out;

  char* ws = (char*)d_ws;
  size_t off = 0;
  auto alloc = [&](size_t elems) {
    __hip_bfloat16* p = (__hip_bfloat16*)(ws + off);
    off += ((elems * 2 + 255) & ~(size_t)255);
    return p;
  };
  __hip_bfloat16* xb  = alloc(8388608);            // x bf16; reused as po half0 after proj1
  __hip_bfloat16* Bt1 = alloc(4608UL * 2048);      // weights^T; reused as po half1 after proj1
  __hip_bfloat16* Bt2 = alloc(4096UL * 512);       // [wuk^T; wuv^T]; reused as ml after proj2
  __hip_bfloat16* woT = alloc(4194304);
  __hip_bfloat16* qcb = alloc(8388608);
  __hip_bfloat16* ckv = alloc(2097152);
  __hip_bfloat16* kcb = alloc(8388608);
  __hip_bfloat16* vcb = alloc(8388608);
  __hip_bfloat16* qrb = alloc(4194304);
  __hip_bfloat16* krb = alloc(4194304);
  __hip_bfloat16* aob = alloc(8388608);
  __hip_bfloat16* vT  = alloc(8388608);            // [32][128][2048]

  k_prep<<<7936, 256, 0, stream>>>(x, xb, w_q, w_qp, w_kp, w_dkv, w_uk, w_uv, w_o,
                                   Bt1, Bt2, woT);

  k_gemm2<2><<<36 * 32, 256, 0, stream>>>(xb, Bt1, 2048, 36, qcb, qrb, krb, ckv, 1.0f);
  k_gemm2<3><<<32 * 32, 256, 0, stream>>>(ckv, Bt2, 512, 32, kcb, vcb, vT, nullptr, 1.0f);

  // dead-buffer reuse: xb (16 MB) and Bt1 (first 16 MB) are adjacent in ws
  // (xb's 16 MB is 256-aligned with no padding gap), so po half0 = xb and
  // half1 = xb + 8388608 elems (= start of Bt1). ml reuses Bt2 (needs 2 MB of 4).
  __hip_bfloat16* po  = xb;
  float*          mlp = (float*)Bt2;

  k_attn_part<<<2048, 256, 0, stream>>>(qcb, kcb, vcb, qrb, krb, vT, po, mlp);
  k_combine<<<4096, 256, 0, stream>>>(po, mlp, aob);

  k_gemm2<1><<<16 * 32, 256, 0, stream>>>(aob, woT, 2048, 16, out, nullptr, nullptr, nullptr, 1.0f);
}